// Round 2
// baseline (520.294 us; speedup 1.0000x reference)
//
#include <hip/hip_runtime.h>
#include <cfloat>

#define NUM_EMB 50
#define EMB_DIM 192
#define ESTRIDE 196  // padded LDS stride (keeps rows 16B-aligned: 196*4 = 49*16)

// ((r0+r1)+(r2+r3))+((r4+r5)+(r6+r7)) — numpy's 8-accumulator combine tree
__device__ __forceinline__ float np_tree8(const float r[8]) {
#pragma clang fp contract(off)
    return ((r[0] + r[1]) + (r[2] + r[3])) + ((r[4] + r[5]) + (r[6] + r[7]));
}

// Bit-exact replica of np.sum(v*v) over 192 contiguous floats:
// pairwise halves of 96, each = 8 stride-8 accumulators + combine tree;
// products rounded separately (contract off).
__device__ float np_sumsq_192(const float* __restrict__ p) {
#pragma clang fp contract(off)
    float tot[2];
#pragma unroll
    for (int h = 0; h < 2; ++h) {
        float r[8];
#pragma unroll
        for (int l = 0; l < 8; ++l) r[l] = 0.f;
        const float* q = p + h * 96;
        for (int t = 0; t < 12; ++t)
#pragma unroll
            for (int l = 0; l < 8; ++l) {
                float v = q[t * 8 + l];
                float pr = v * v;
                r[l] = r[l] + pr;
            }
        tot[h] = np_tree8(r);
    }
    return tot[0] + tot[1];
}

// One thread per row, x row RESIDENT IN REGISTERS (192 VGPRs), k-loop outer.
//
// R1 post-mortem: with k-loop inner + full unroll, the compiler register-
// minimized (VGPR=56!) and re-streamed x from L1/L2 inside the k-loop ->
// cache-bandwidth bound at ~187us regardless of how e was delivered.
// This version pins the x row in VGPRs (loaded once), iterates k outermost
// with ONE sequential-FMA chain per k (identical numpy/BLAS order), and
// interleaves two k-chains for ILP. e reads are wave-uniform -> scalar/L1
// broadcast, fully hidden under the ~770-cycle FMA chain per k.
// __launch_bounds__(256,2) grants a 256-VGPR budget so the allocator has no
// reason to evict xr[].
__global__ __launch_bounds__(256, 2) void vq_fused(
    const float* __restrict__ x, const float* __restrict__ ew,
    float* __restrict__ out_q, float* __restrict__ out_idx,
    float* __restrict__ out_loss, int N)
{
    __shared__ __align__(16) float sE[NUM_EMB * ESTRIDE];  // for sB + output write
    __shared__ float sB[NUM_EMB];

    for (int i = threadIdx.x; i < NUM_EMB * EMB_DIM; i += blockDim.x) {
        int k = i / EMB_DIM, j = i - k * EMB_DIM;
        sE[k * ESTRIDE + j] = ew[i];
    }
    __syncthreads();
    if (threadIdx.x < NUM_EMB)
        sB[threadIdx.x] = np_sumsq_192(&sE[threadIdx.x * ESTRIDE]);  // row contiguous
    __syncthreads();

    const int row = blockIdx.x * blockDim.x + threadIdx.x;  // grid = N/256 exact
    const float4* xg = (const float4*)(x + (size_t)row * EMB_DIM);

    // ---- load full x row into registers (once; the ONLY x read) ----
    float4 xr[48];
#pragma unroll
    for (int q = 0; q < 48; ++q) xr[q] = xg[q];

    // ---- a = np.sum(x*x) with exact numpy pairwise structure ----
    float a;
    {
#pragma clang fp contract(off)
        float tot[2];
#pragma unroll
        for (int h = 0; h < 2; ++h) {
            float r[8];
#pragma unroll
            for (int l = 0; l < 8; ++l) r[l] = 0.f;
#pragma unroll
            for (int t = 0; t < 12; ++t) {
                // elements h*96 + t*8 + [0..7] = two consecutive float4
                const float4 va = xr[h * 24 + t * 2];
                const float4 vb = xr[h * 24 + t * 2 + 1];
                float p0 = va.x * va.x; r[0] = r[0] + p0;
                float p1 = va.y * va.y; r[1] = r[1] + p1;
                float p2 = va.z * va.z; r[2] = r[2] + p2;
                float p3 = va.w * va.w; r[3] = r[3] + p3;
                float p4 = vb.x * vb.x; r[4] = r[4] + p4;
                float p5 = vb.y * vb.y; r[5] = r[5] + p5;
                float p6 = vb.z * vb.z; r[6] = r[6] + p6;
                float p7 = vb.w * vb.w; r[7] = r[7] + p7;
            }
            tot[h] = np_tree8(r);
        }
        a = tot[0] + tot[1];
    }

    // ---- k-loop outer: 2 interleaved sequential-FMA dot chains per iter ----
    // Chain order per k is ascending j (numpy/BLAS sgemm order) — bit-exact.
    // k-loop stays ROLLED (25 iters, ~2.5KB body): no I$ blowup, no
    // register-minimizing unroll heuristics.
    float best = FLT_MAX; int bidx = 0;
    for (int kp = 0; kp < NUM_EMB / 2; ++kp) {
        const float* e0 = ew + (size_t)(2 * kp) * EMB_DIM;
        const float* e1 = e0 + EMB_DIM;
        float a0 = 0.f, a1 = 0.f;
#pragma unroll
        for (int q = 0; q < 48; ++q) {
            const float4 ea = *(const float4*)&e0[q * 4];  // wave-uniform
            const float4 eb = *(const float4*)&e1[q * 4];  // wave-uniform
            const float4 xv = xr[q];
            a0 = __builtin_fmaf(xv.x, ea.x, a0);
            a0 = __builtin_fmaf(xv.y, ea.y, a0);
            a0 = __builtin_fmaf(xv.z, ea.z, a0);
            a0 = __builtin_fmaf(xv.w, ea.w, a0);
            a1 = __builtin_fmaf(xv.x, eb.x, a1);
            a1 = __builtin_fmaf(xv.y, eb.y, a1);
            a1 = __builtin_fmaf(xv.z, eb.z, a1);
            a1 = __builtin_fmaf(xv.w, eb.w, a1);
        }
        {
#pragma clang fp contract(off)
            const float sb0 = sB[2 * kp], sb1 = sB[2 * kp + 1];
            float t0 = a + sb0;       // fl(a + b_k)
            float u0 = 2.0f * a0;     // exact x2
            float d0 = t0 - u0;       // fl(t1 - u)
            if (d0 < best) { best = d0; bidx = 2 * kp; }      // strict <
            float t1 = a + sb1;
            float u1 = 2.0f * a1;
            float d1 = t1 - u1;
            if (d1 < best) { best = d1; bidx = 2 * kp + 1; }  // strict <
        }
    }
    out_idx[row] = (float)bidx;

    // ---- loss: per-wave shuffle reduce + one atomic ----
    float contrib = best;
#pragma unroll
    for (int off = 1; off < 64; off <<= 1) contrib += __shfl_xor(contrib, off);
    if ((threadIdx.x & 63) == 0) atomicAdd(out_loss, contrib);

    // ---- fused coalesced quantized-row write (octet pattern) ----
    {
        const int lane = threadIdx.x & 63;
        const int c = lane & 7;
        const int rr = lane >> 3;
        const int waveRow0 = row & ~63;  // first row owned by this wave
#pragma unroll
        for (int g = 0; g < 8; ++g) {
            const int kk = __shfl(bidx, g * 8 + rr);
            const int wrow = waveRow0 + g * 8 + rr;
            float4* qrow = (float4*)(out_q + (size_t)wrow * EMB_DIM);
            const float* erow = &sE[kk * ESTRIDE];
#pragma unroll
            for (int t = 0; t < 6; ++t)
                qrow[c + 8 * t] = *(const float4*)&erow[(c + 8 * t) * 4];
        }
    }
}

__global__ void vq_init(float* out_loss) { out_loss[0] = 0.f; out_loss[1] = 0.f; }

__global__ void vq_finalize(float* __restrict__ out_loss, int N)
{
    double mean = (double)out_loss[0] / ((double)N * (double)EMB_DIM);
    out_loss[0] = (float)(1.25 * mean);  // (1 + BETA) * mean min-dist / elems
    out_loss[1] = 0.f;                   // contrastloss
}

extern "C" void kernel_launch(void* const* d_in, const int* in_sizes, int n_in,
                              void* d_out, int out_size, void* d_ws, size_t ws_size,
                              hipStream_t stream)
{
    const float* x  = (const float*)d_in[0];
    const float* ew = (const float*)d_in[1];
    const int N = in_sizes[0] / EMB_DIM;  // 262144 (divisible by 256)

    float* out_q    = (float*)d_out;
    float* out_idx  = out_q + (size_t)N * EMB_DIM;
    float* out_loss = out_idx + N;

    vq_init<<<1, 1, 0, stream>>>(out_loss);
    vq_fused<<<N / 256, 256, 0, stream>>>(x, ew, out_q, out_idx, out_loss, N);
    vq_finalize<<<1, 1, 0, stream>>>(out_loss, N);
}